// Round 5
// baseline (1834.290 us; speedup 1.0000x reference)
//
#include <hip/hip_runtime.h>

typedef float f32x4 __attribute__((ext_vector_type(4)));
typedef __bf16 bf16x8 __attribute__((ext_vector_type(8)));
typedef __bf16 bf16x4 __attribute__((ext_vector_type(4)));
typedef unsigned int u32x4 __attribute__((ext_vector_type(4)));
typedef unsigned int u32x2 __attribute__((ext_vector_type(2)));

#define DI __device__ __forceinline__

constexpr int B_ = 4, T_ = 2048, C_ = 2048, H_ = 32;
constexpr int M_ = B_ * T_;  // 8192 rows

DI unsigned short f2bf(float f) {
  unsigned u = __float_as_uint(f);
  return (unsigned short)((u + 0x7FFFu + ((u >> 16) & 1u)) >> 16);
}
DI float bf2f(unsigned short h) { return __uint_as_float(((unsigned)h) << 16); }

DI void gl16(const void* g, void* l) {
  __builtin_amdgcn_global_load_lds(
      (__attribute__((address_space(1))) const unsigned int*)g,
      (__attribute__((address_space(3))) unsigned int*)l, 16, 0, 0);
}

// 16-lane sum, pure DPP: quad_perm pair -> quad-uniform, then row_ror:4 + row_ror:8.
DI float rsum16(float x) {
  int t = __builtin_amdgcn_update_dpp(0, __float_as_int(x), 0xB1, 0xF, 0xF, true);
  x += __int_as_float(t);
  t = __builtin_amdgcn_update_dpp(0, __float_as_int(x), 0x4E, 0xF, 0xF, true);
  x += __int_as_float(t);
  t = __builtin_amdgcn_update_dpp(0, __float_as_int(x), 0x124, 0xF, 0xF, true);
  x += __int_as_float(t);
  t = __builtin_amdgcn_update_dpp(0, __float_as_int(x), 0x128, 0xF, 0xF, true);
  x += __int_as_float(t);
  return x;
}

// ---------------- transpose f32 (R x C) -> bf16 (C x R) ----------------
__global__ __launch_bounds__(256) void k_transpose(const float* __restrict__ in,
                                                   unsigned short* __restrict__ out,
                                                   int R, int C) {
  __shared__ float tile[32][33];
  int c0 = blockIdx.x * 32, r0 = blockIdx.y * 32;
  int tx = threadIdx.x & 31, ty = threadIdx.x >> 5;
#pragma unroll
  for (int i = 0; i < 4; ++i) {
    int r = r0 + ty * 4 + i, c = c0 + tx;
    if (r < R && c < C) tile[ty * 4 + i][tx] = in[(size_t)r * C + c];
  }
  __syncthreads();
#pragma unroll
  for (int i = 0; i < 4; ++i) {
    int c = c0 + ty * 4 + i, r = r0 + tx;
    if (r < R && c < C) out[(size_t)c * R + r] = f2bf(tile[tx][ty * 4 + i]);
  }
}

// ---------------- token-shift mix prep (1 or 2 coef sets) ----------------
DI void mix_emit(const float* coef, int c0, size_t off,
                 const float* xv, const float* dx, unsigned short* dst) {
  unsigned short u[8];
#pragma unroll
  for (int i = 0; i < 2; ++i) {
    f32x4 cf = *(const f32x4*)(coef + c0 + i * 4);
#pragma unroll
    for (int j = 0; j < 4; ++j) u[i * 4 + j] = f2bf(xv[i * 4 + j] + dx[i * 4 + j] * cf[j]);
  }
  u32x4 pv;
#pragma unroll
  for (int j = 0; j < 4; ++j) pv[j] = (unsigned)u[2 * j] | ((unsigned)u[2 * j + 1] << 16);
  *(u32x4*)(dst + off) = pv;
}

__global__ __launch_bounds__(256) void k_prep2(
    const float* __restrict__ x, const float* __restrict__ xprev,
    const float* __restrict__ cA, const float* __restrict__ cB,
    unsigned short* __restrict__ XA, unsigned short* __restrict__ XB) {
  int bt = blockIdx.x;
  int t = bt & (T_ - 1);
  int c0 = threadIdx.x * 8;
  size_t off = (size_t)bt * C_ + c0;
  const float* xp = x + off;
  const float* pp = t ? (xp - C_) : (xprev + (size_t)(bt >> 11) * C_ + c0);
  float xv[8], dx[8];
#pragma unroll
  for (int i = 0; i < 2; ++i) {
    f32x4 a = *(const f32x4*)(xp + i * 4);
    f32x4 p = *(const f32x4*)(pp + i * 4);
#pragma unroll
    for (int j = 0; j < 4; ++j) { xv[i * 4 + j] = a[j]; dx[i * 4 + j] = p[j] - a[j]; }
  }
  mix_emit(cA, c0, off, xv, dx, XA);
  mix_emit(cB, c0, off, xv, dx, XB);
}

__global__ __launch_bounds__(256) void k_prep1(
    const float* __restrict__ x, const float* __restrict__ xprev,
    const float* __restrict__ cA, unsigned short* __restrict__ XA) {
  int bt = blockIdx.x;
  int t = bt & (T_ - 1);
  int c0 = threadIdx.x * 8;
  size_t off = (size_t)bt * C_ + c0;
  const float* xp = x + off;
  const float* pp = t ? (xp - C_) : (xprev + (size_t)(bt >> 11) * C_ + c0);
  float xv[8], dx[8];
#pragma unroll
  for (int i = 0; i < 2; ++i) {
    f32x4 a = *(const f32x4*)(xp + i * 4);
    f32x4 p = *(const f32x4*)(pp + i * 4);
#pragma unroll
    for (int j = 0; j < 4; ++j) { xv[i * 4 + j] = a[j]; dx[i * 4 + j] = p[j] - a[j]; }
  }
  mix_emit(cA, c0, off, xv, dx, XA);
}

// fused token-shift mix staging (for small down-GEMMs only)
DI void stage_mix(const float* __restrict__ x, const float* __restrict__ xprev,
                  const float* __restrict__ coef, unsigned short* As,
                  int m0, int kt, int wv, int lane) {
  const int lr = lane >> 3, lc = (lane & 7) * 8;
  f32x4 c0 = *(const f32x4*)(coef + kt + lc);
  f32x4 c1 = *(const f32x4*)(coef + kt + lc + 4);
#pragma unroll
  for (int i = 0; i < 4; ++i) {
    int chunk = wv * 4 + i;
    int r = chunk * 8 + lr;
    int m = m0 + r;
    const float* xp = x + (size_t)m * C_ + kt + lc;
    const float* pp = (m & (T_ - 1)) ? (xp - C_)
                                     : (xprev + (size_t)(m >> 11) * C_ + kt + lc);
    f32x4 xv0 = *(const f32x4*)xp, xv1 = *(const f32x4*)(xp + 4);
    f32x4 pv0 = *(const f32x4*)pp, pv1 = *(const f32x4*)(pp + 4);
    unsigned short u[8];
#pragma unroll
    for (int j = 0; j < 4; ++j) u[j] = f2bf(xv0[j] + (pv0[j] - xv0[j]) * c0[j]);
#pragma unroll
    for (int j = 0; j < 4; ++j) u[4 + j] = f2bf(xv1[j] + (pv1[j] - xv1[j]) * c1[j]);
    u32x4 pk;
#pragma unroll
    for (int j = 0; j < 4; ++j) pk[j] = (unsigned)u[2 * j] | ((unsigned)u[2 * j + 1] << 16);
    *(u32x4*)((char*)As + chunk * 1024 + lane * 16) = pk;
  }
}

// ---------------- big GEMM: 128x128 tile, K=2048, plain bf16 A (gl16 staging) ----
// EPI 0: RB = bf16(acc)
// EPI 1: VB = bf16(acc + (vfirst - acc)*svb)
// EPI 2: kk-norm fused: KB, AHB, BHB
// EPI 3: f32 store (final output GEMM)
template <int EPI>
__global__ __launch_bounds__(256, 2) void k_gemm_big(
    const unsigned short* __restrict__ A,
    const unsigned short* __restrict__ Bt,
    float* __restrict__ outF, unsigned short* __restrict__ outB,
    const unsigned short* __restrict__ svb, const float* __restrict__ vfirst,
    const unsigned short* __restrict__ abf,
    const float* __restrict__ k_k, const float* __restrict__ k_a,
    unsigned short* __restrict__ ahb, unsigned short* __restrict__ bhb) {
  __shared__ __align__(16) unsigned short As[128][64];
  __shared__ __align__(16) unsigned short Bs[128][64];
  const int tid = threadIdx.x, lane = tid & 63, wv = tid >> 6;
  const int m0 = blockIdx.y * 128, n0 = blockIdx.x * 128;
  const int wm = (wv >> 1) * 64, wn = (wv & 1) * 64;
  const int lr = lane >> 3, lc = (lane & 7) * 8;
  f32x4 acc[4][4] = {};
  for (int kt = 0; kt < C_; kt += 64) {
    __syncthreads();
#pragma unroll
    for (int i = 0; i < 4; ++i) {
      int chunk = wv * 4 + i, r = chunk * 8 + lr;
      gl16(A + (size_t)(m0 + r) * C_ + kt + lc, (char*)&As[0][0] + chunk * 1024);
      gl16(Bt + (size_t)(n0 + r) * C_ + kt + lc, (char*)&Bs[0][0] + chunk * 1024);
    }
    __syncthreads();
    const int rr = lane & 15;
#pragma unroll
    for (int kh = 0; kh < 2; ++kh) {
      const int kof = kh * 32 + (lane >> 4) * 8;
      bf16x8 af[4], bfv[4];
#pragma unroll
      for (int i = 0; i < 4; ++i) af[i] = *(const bf16x8*)&As[wm + i * 16 + rr][kof];
#pragma unroll
      for (int j = 0; j < 4; ++j) bfv[j] = *(const bf16x8*)&Bs[wn + j * 16 + rr][kof];
#pragma unroll
      for (int i = 0; i < 4; ++i)
#pragma unroll
        for (int j = 0; j < 4; ++j)
          acc[i][j] = __builtin_amdgcn_mfma_f32_16x16x32_bf16(af[i], bfv[j], acc[i][j], 0, 0, 0);
    }
  }
  const int cr = (lane >> 4) * 4, cc2 = lane & 15;
  if constexpr (EPI == 2) {
    float kkv[4], kav[4];
#pragma unroll
    for (int j = 0; j < 4; ++j) {
      int col = n0 + wn + j * 16 + cc2;
      kkv[j] = k_k[col];
      kav[j] = k_a[col];
    }
#pragma unroll
    for (int i = 0; i < 4; ++i)
#pragma unroll
      for (int q = 0; q < 4; ++q) {
        int row = m0 + wm + i * 16 + cr + q;
        float kk4[4], p = 0.f;
#pragma unroll
        for (int j = 0; j < 4; ++j) {
          float kkc = acc[i][j][q] * kkv[j];
          kk4[j] = kkc;
          p += kkc * kkc;
        }
        p += __shfl_xor(p, 1); p += __shfl_xor(p, 2);
        p += __shfl_xor(p, 4); p += __shfl_xor(p, 8);
        float inv = 1.f / fmaxf(sqrtf(p), 1e-12f);
#pragma unroll
        for (int j = 0; j < 4; ++j) {
          int col = n0 + wn + j * 16 + cc2;
          size_t off = (size_t)row * C_ + col;
          float kkn = kk4[j] * inv;
          float a = bf2f(abf[off]);
          ahb[off] = f2bf(-kkn);
          bhb[off] = f2bf(kkn * a);
          outB[off] = f2bf(acc[i][j][q] * (1.f + (a - 1.f) * kav[j]));
        }
      }
  } else {
#pragma unroll
    for (int i = 0; i < 4; ++i)
#pragma unroll
      for (int j = 0; j < 4; ++j)
#pragma unroll
        for (int q = 0; q < 4; ++q) {
          int row = m0 + wm + i * 16 + cr + q;
          int col = n0 + wn + j * 16 + cc2;
          size_t off = (size_t)row * C_ + col;
          float v = acc[i][j][q];
          if constexpr (EPI == 0) {
            outB[off] = f2bf(v);
          } else if constexpr (EPI == 1) {
            float s = bf2f(svb[off]);
            outB[off] = f2bf(v + (vfirst[off] - v) * s);
          } else {
            outF[off] = v;
          }
        }
  }
}

// ---------------- down GEMM: H(bf16, MxN) = act(mix @ Bt^T), N in {32,64,128} --
// ACT: 0 none, 1 tanh, 2 sigmoid. FUSED: compute mix on the fly vs plain bf16 A.
template <int N, int ACT, bool FUSED>
__global__ __launch_bounds__(256, 2) void k_down(
    const unsigned short* __restrict__ A,
    const float* __restrict__ x, const float* __restrict__ xprev,
    const float* __restrict__ coef, const unsigned short* __restrict__ Bt,
    unsigned short* __restrict__ out) {
  __shared__ __align__(16) unsigned short As[128][64];
  __shared__ __align__(16) unsigned short Bs[N][64];
  const int tid = threadIdx.x, lane = tid & 63, wv = tid >> 6;
  const int m0 = blockIdx.x * 128;
  const int wm = wv * 32;
  const int lr = lane >> 3, lc = (lane & 7) * 8;
  f32x4 acc[2][N / 16] = {};
  for (int kt = 0; kt < C_; kt += 64) {
    __syncthreads();
    if constexpr (FUSED) {
      stage_mix(x, xprev, coef, &As[0][0], m0, kt, wv, lane);
    } else {
#pragma unroll
      for (int i = 0; i < 4; ++i) {
        int chunk = wv * 4 + i, r = chunk * 8 + lr;
        gl16(A + (size_t)(m0 + r) * C_ + kt + lc, (char*)&As[0][0] + chunk * 1024);
      }
    }
#pragma unroll
    for (int i = 0; i < N / 32; ++i) {
      int chunk = wv * (N / 32) + i, r = chunk * 8 + lr;
      gl16(Bt + (size_t)r * C_ + kt + lc, (char*)&Bs[0][0] + chunk * 1024);
    }
    __syncthreads();
    const int rr = lane & 15;
#pragma unroll
    for (int kh = 0; kh < 2; ++kh) {
      const int kof = kh * 32 + (lane >> 4) * 8;
      bf16x8 af[2], bfv[N / 16];
#pragma unroll
      for (int i = 0; i < 2; ++i) af[i] = *(const bf16x8*)&As[wm + i * 16 + rr][kof];
#pragma unroll
      for (int j = 0; j < N / 16; ++j) bfv[j] = *(const bf16x8*)&Bs[j * 16 + rr][kof];
#pragma unroll
      for (int i = 0; i < 2; ++i)
#pragma unroll
        for (int j = 0; j < N / 16; ++j)
          acc[i][j] = __builtin_amdgcn_mfma_f32_16x16x32_bf16(af[i], bfv[j], acc[i][j], 0, 0, 0);
    }
  }
  const int cr = (lane >> 4) * 4, cc2 = lane & 15;
#pragma unroll
  for (int i = 0; i < 2; ++i)
#pragma unroll
    for (int j = 0; j < N / 16; ++j)
#pragma unroll
      for (int q = 0; q < 4; ++q) {
        int row = m0 + wm + i * 16 + cr + q;
        int col = j * 16 + cc2;
        float v = acc[i][j][q];
        if (ACT == 1) v = tanhf(v);
        else if (ACT == 2) v = 1.f / (1.f + expf(-v));
        out[(size_t)row * N + col] = f2bf(v);
      }
}

// ---------------- up GEMM (K in {32,64,128}), single K pass ----------------
// MODE 0: wd = exp(-exp(-softplus(-(bias+up)) - 0.5)) -> outF (f32)
// MODE 1: sigmoid(bias+up) -> outB (bf16)
// MODE 3: up -> outB (bf16)
template <int K, int MODE>
__global__ __launch_bounds__(256, 2) void k_up(
    const unsigned short* __restrict__ A, const unsigned short* __restrict__ Bt,
    const float* __restrict__ bias, float* __restrict__ outF,
    unsigned short* __restrict__ outB) {
  __shared__ __align__(16) unsigned short As[128][K];
  __shared__ __align__(16) unsigned short Bs[128][K];
  const int tid = threadIdx.x, lane = tid & 63, wv = tid >> 6;
  const int m0 = blockIdx.y * 128, n0 = blockIdx.x * 128;
  const int wm = (wv >> 1) * 64, wn = (wv & 1) * 64;
  constexpr int LPR = K / 8;
  constexpr int RPC = 64 / LPR;
  const int lr = lane / LPR, lc = (lane % LPR) * 8;
  f32x4 acc[4][4] = {};
#pragma unroll
  for (int i = 0; i < K / 16; ++i) {
    int chunk = wv * (K / 16) + i;
    int r = chunk * RPC + lr;
    gl16(A + (size_t)(m0 + r) * K + lc, (char*)&As[0][0] + chunk * 1024);
    gl16(Bt + (size_t)(n0 + r) * K + lc, (char*)&Bs[0][0] + chunk * 1024);
  }
  __syncthreads();
  const int rr = lane & 15;
#pragma unroll
  for (int ks = 0; ks < K / 32; ++ks) {
    const int kof = ks * 32 + (lane >> 4) * 8;
    bf16x8 af[4], bfv[4];
#pragma unroll
    for (int i = 0; i < 4; ++i) af[i] = *(const bf16x8*)&As[wm + i * 16 + rr][kof];
#pragma unroll
    for (int j = 0; j < 4; ++j) bfv[j] = *(const bf16x8*)&Bs[wn + j * 16 + rr][kof];
#pragma unroll
    for (int i = 0; i < 4; ++i)
#pragma unroll
      for (int j = 0; j < 4; ++j)
        acc[i][j] = __builtin_amdgcn_mfma_f32_16x16x32_bf16(af[i], bfv[j], acc[i][j], 0, 0, 0);
  }
  const int cr = (lane >> 4) * 4, cc2 = lane & 15;
#pragma unroll
  for (int i = 0; i < 4; ++i)
#pragma unroll
    for (int j = 0; j < 4; ++j)
#pragma unroll
      for (int q = 0; q < 4; ++q) {
        int row = m0 + wm + i * 16 + cr + q;
        int col = n0 + wn + j * 16 + cc2;
        size_t off = (size_t)row * C_ + col;
        float up = acc[i][j][q];
        if (MODE == 0) {
          float z = -(bias[col] + up);
          float sp = fmaxf(z, 0.f) + log1pf(expf(-fabsf(z)));
          outF[off] = expf(-expf(-sp - 0.5f));
        } else if (MODE == 1) {
          outB[off] = f2bf(1.f / (1.f + expf(-(bias[col] + up))));
        } else {
          outB[off] = f2bf(up);
        }
      }
}

// ---------------- WKV recurrent scan: asm-pinned register pipeline ----------------
// 2048 one-wave blocks. Block p: wq = p>>7 (row-quad), bh = p&127 (same-XCD for
// one (b,h)'s 16 waves). Lane: rl = lane>>4 (row 0..3), e = lane&15 (col-quad).
// Depth-8 slot rotation; loads are asm volatile (SGPR base + voffset) so the
// compiler cannot collapse the pipeline (R4: VGPR=48 proved it sank the loads).
// Counted s_waitcnt vmcnt(42) = 7 younger ISSUEs x 6 loads; sched_barrier after.
__global__ __launch_bounds__(64, 2) void k_scan(
    const unsigned short* __restrict__ RB, const float* __restrict__ WD,
    const unsigned short* __restrict__ KB, const unsigned short* __restrict__ VB,
    const unsigned short* __restrict__ AHB, const unsigned short* __restrict__ BHB,
    const float* __restrict__ s0, float* __restrict__ out) {
  const int lane = threadIdx.x & 63;
  const int p = blockIdx.x;
  const int wq = p >> 7, bh = p & 127;
  const int b = bh >> 5, h = bh & 31;
  const int e = lane & 15, rl = lane >> 4;
  const int row = wq * 4 + rl;
  const size_t base = (size_t)b * T_ * C_ + h * 64;
  f32x4 S = *(const f32x4*)(s0 + ((size_t)(b * H_ + h) * 64 + row) * 64 + e * 4);
  asm volatile("" : "+v"(S));  // force S-load waitcnt BEFORE the prologue issues

  const unsigned long long bR = (unsigned long long)(RB + base);
  const unsigned long long bK = (unsigned long long)(KB + base);
  const unsigned long long bA = (unsigned long long)(AHB + base);
  const unsigned long long bB = (unsigned long long)(BHB + base);
  const unsigned long long bW = (unsigned long long)(WD + base);
  const unsigned long long bV = (unsigned long long)(VB + base);
  unsigned voE = e * 8;   // byte offset into bf16 streams (4 elems * 2B)
  unsigned voW = e * 16;  // byte offset into f32 wd stream
  unsigned voV = row * 2;

#define DECL(n) u32x2 R_##n, K_##n, A_##n, Bv_##n; f32x4 W_##n; unsigned V_##n;
  DECL(0) DECL(1) DECL(2) DECL(3) DECL(4) DECL(5) DECL(6) DECL(7)

#define ISSUE(n)                                                                            \
  asm volatile("global_load_dwordx2 %0, %1, %2" : "=v"(R_##n) : "v"(voE), "s"(bR) : "memory"); \
  asm volatile("global_load_dwordx2 %0, %1, %2" : "=v"(K_##n) : "v"(voE), "s"(bK) : "memory"); \
  asm volatile("global_load_dwordx2 %0, %1, %2" : "=v"(A_##n) : "v"(voE), "s"(bA) : "memory"); \
  asm volatile("global_load_dwordx2 %0, %1, %2" : "=v"(Bv_##n) : "v"(voE), "s"(bB) : "memory"); \
  asm volatile("global_load_dwordx4 %0, %1, %2" : "=v"(W_##n) : "v"(voW), "s"(bW) : "memory"); \
  asm volatile("global_load_ushort %0, %1, %2" : "=v"(V_##n) : "v"(voV), "s"(bV) : "memory"); \
  voE += 4096; voW += 8192; voV += 4096;

#define LO_(d) __uint_as_float((d) << 16)
#define HI_(d) __uint_as_float((d) & 0xffff0000u)

#define STEP(n, t)                                                        \
  {                                                                       \
    asm volatile("s_waitcnt vmcnt(42)" ::: "memory");                     \
    __builtin_amdgcn_sched_barrier(0);                                    \
    float a0 = LO_(A_##n[0]), a1 = HI_(A_##n[0]);                         \
    float a2 = LO_(A_##n[1]), a3 = HI_(A_##n[1]);                         \
    float sa = fmaf(S[0], a0, S[1] * a1) + fmaf(S[2], a2, S[3] * a3);     \
    sa = rsum16(sa);                                                      \
    float k0 = LO_(K_##n[0]), k1 = HI_(K_##n[0]);                         \
    float k2 = LO_(K_##n[1]), k3 = HI_(K_##n[1]);                         \
    float b0 = LO_(Bv_##n[0]), b1 = HI_(Bv_##n[0]);                       \
    float b2 = LO_(Bv_##n[1]), b3 = HI_(Bv_##n[1]);                       \
    float r0 = LO_(R_##n[0]), r1 = HI_(R_##n[0]);                         \
    float r2 = LO_(R_##n[1]), r3 = HI_(R_##n[1]);                         \
    float vi = __uint_as_float(V_##n << 16);                              \
    S[0] = fmaf(S[0], W_##n[0], fmaf(sa, b0, vi * k0));                   \
    S[1] = fmaf(S[1], W_##n[1], fmaf(sa, b1, vi * k1));                   \
    S[2] = fmaf(S[2], W_##n[2], fmaf(sa, b2, vi * k2));                   \
    S[3] = fmaf(S[3], W_##n[3], fmaf(sa, b3, vi * k3));                   \
    float o = fmaf(S[0], r0, S[1] * r1) + fmaf(S[2], r2, S[3] * r3);      \
    o = rsum16(o);                                                        \
    if (e == 0) out[base + (size_t)(t) * C_ + row] = o;                   \
  }

  ISSUE(0) ISSUE(1) ISSUE(2) ISSUE(3) ISSUE(4) ISSUE(5) ISSUE(6)
#pragma unroll 1
  for (int t = 0; t < T_; t += 8) {
    ISSUE(7) STEP(0, t)
    ISSUE(0) STEP(1, t + 1)
    ISSUE(1) STEP(2, t + 2)
    ISSUE(2) STEP(3, t + 3)
    ISSUE(3) STEP(4, t + 4)
    ISSUE(4) STEP(5, t + 5)
    ISSUE(5) STEP(6, t + 6)
    ISSUE(6) STEP(7, t + 7)
  }
#undef DECL
#undef ISSUE
#undef STEP
#undef LO_
#undef HI_
}

// ---------------- GroupNorm + bonus + gate (wave per (b,t,h)) ----------------
__global__ __launch_bounds__(256) void k_gn(
    const float* __restrict__ o, const unsigned short* __restrict__ rb,
    const unsigned short* __restrict__ kb, const unsigned short* __restrict__ v,
    const unsigned short* __restrict__ g, const float* __restrict__ r_k,
    const float* __restrict__ lnw, const float* __restrict__ lnb,
    unsigned short* __restrict__ outg) {
  int wid = blockIdx.x * 4 + (threadIdx.x >> 6);
  int lane = threadIdx.x & 63;
  int h = wid & (H_ - 1);
  size_t bt = (size_t)(wid >> 5);
  size_t off = bt * C_ + h * 64 + lane;
  int c = h * 64 + lane;
  float x = o[off];
  float mu = x;
#pragma unroll
  for (int m = 1; m < 64; m <<= 1) mu += __shfl_xor(mu, m);
  mu *= (1.f / 64.f);
  float d = x - mu;
  float var = d * d;
#pragma unroll
  for (int m = 1; m < 64; m <<= 1) var += __shfl_xor(var, m);
  var *= (1.f / 64.f);
  float y = d * rsqrtf(var + 6.4e-4f) * lnw[c] + lnb[c];
  float bd = bf2f(rb[off]) * bf2f(kb[off]) * r_k[c];
#pragma unroll
  for (int m = 1; m < 64; m <<= 1) bd += __shfl_xor(bd, m);
  float res = (y + bd * bf2f(v[off])) * bf2f(g[off]);
  outg[off] = f2bf(res);
}

// ---------------- host launch ----------------
extern "C" void kernel_launch(void* const* d_in, const int* in_sizes, int n_in,
                              void* d_out, int out_size, void* d_ws, size_t ws_size,
                              hipStream_t stream) {
  const float* x      = (const float*)d_in[0];
  const float* vfirst = (const float*)d_in[1];
  const float* xprev  = (const float*)d_in[2];
  const float* wkv0   = (const float*)d_in[3];
  const float* x_r = (const float*)d_in[4];
  const float* x_w = (const float*)d_in[5];
  const float* x_k = (const float*)d_in[6];
  const float* x_v = (const float*)d_in[7];
  const float* x_a = (const float*)d_in[8];
  const float* x_g = (const float*)d_in[9];
  const float* w0 = (const float*)d_in[10];
  const float* w1 = (const float*)d_in[11];
  const float* w2 = (const float*)d_in[12];
  const float* a0 = (const float*)d_in[13];
  const float* a1 = (const float*)d_in[14];
  const float* a2 = (const float*)d_in[15];
  const float* v0 = (const float*)d_in[16];
  const float* v1 = (const float*)d_in[17];
  const float* v2 = (const float*)d_in[18];
  const float* g1 = (const float*)d_in[19];
  const float* g2 = (const float*)d_in[20];
  const float* k_k = (const float*)d_in[21];
  const float* k_a = (const float*)d_in[22];
  const float* r_k = (const float*)d_in[23];
  const float* Wr = (const float*)d_in[24];
  const float* Wk = (const float*)d_in[25];
  const float* Wv = (const float*)d_in[26];
  const float* Wo = (const float*)d_in[27];
  const float* lnw = (const float*)d_in[28];
  const float* lnb = (const float*)d_in[29];
  float* out = (float*)d_out;
  char* ws = (char*)d_ws;

  // ---- workspace layout (~239 MiB + pad) ----
  size_t woff = 0;
  auto alloc = [&](size_t n) { char* p = ws + woff; woff += n; return p; };
  char* R1 = alloc(67108864);                       // ABF|SVB -> WD (f32)
  unsigned short* ABF = (unsigned short*)R1;
  unsigned short* SVB = (unsigned short*)(R1 + 33554432);
  float* WD = (float*)R1;
  unsigned short* WT  = (unsigned short*)alloc(8388608);   // transposed big weight
  unsigned short* W1T = (unsigned short*)alloc(262144);
  unsigned short* A1T = (unsigned short*)alloc(262144);
  unsigned short* V1T = (unsigned short*)alloc(131072);
  unsigned short* G1T = (unsigned short*)alloc(524288);
  unsigned short* W2T = (unsigned short*)alloc(262144);
  unsigned short* A2T = (unsigned short*)alloc(262144);
  unsigned short* V2T = (unsigned short*)alloc(131072);
  unsigned short* G2T = (unsigned short*)alloc(524288);
  unsigned short* HWB = (unsigned short*)alloc(1048576);
  unsigned short* HAB = (unsigned short*)alloc(1048576);
  unsigned short* HVB = (unsigned short*)alloc(524288);
  unsigned short* HGB = (unsigned short*)alloc(2097152);
  unsigned short* RB  = (unsigned short*)alloc(33554432);
  unsigned short* KB  = (unsigned short*)alloc(33554432);
  unsigned short* VB  = (unsigned short*)alloc(33554432);
  unsigned short* AHB = (unsigned short*)alloc(33554432);
  unsigned short* BHB = (unsigned short*)alloc(33554432);
  alloc(65536);  // pad: scan over-issue (7 steps x 4KB) reads stay mapped
  // Temporal overlays (regions dead at the time of each use):
  unsigned short* XMr = VB;   // x_r mix: dead once V-GEMM writes VB
  unsigned short* XMv = KB;   // x_v mix: dead once K-GEMM writes KB
  unsigned short* XMk = SVB;  // x_k mix: SVB dead after V-GEMM; WD overlays later
  unsigned short* GBF  = AHB; // post-scan overlay (AHB dead)
  unsigned short* OUTG = BHB; // post-scan overlay (BHB dead)

  dim3 blk(256);
  dim3 gg(16, 64);

  // small weight transposes (K-contiguous layouts)
  k_transpose<<<dim3(2, 64), blk, 0, stream>>>(w1, W1T, 2048, 64);
  k_transpose<<<dim3(2, 64), blk, 0, stream>>>(a1, A1T, 2048, 64);
  k_transpose<<<dim3(1, 64), blk, 0, stream>>>(v1, V1T, 2048, 32);
  k_transpose<<<dim3(4, 64), blk, 0, stream>>>(g1, G1T, 2048, 128);
  k_transpose<<<dim3(64, 2), blk, 0, stream>>>(w2, W2T, 64, 2048);
  k_transpose<<<dim3(64, 2), blk, 0, stream>>>(a2, A2T, 64, 2048);
  k_transpose<<<dim3(64, 1), blk, 0, stream>>>(v2, V2T, 32, 2048);
  k_transpose<<<dim3(64, 4), blk, 0, stream>>>(g2, G2T, 128, 2048);

  // mix prep for r and v (x read once, two bf16 mixes out)
  k_prep2<<<dim3(M_), blk, 0, stream>>>(x, xprev, x_r, x_v, XMr, XMv);

  // a-chain (fused mix), v-chain (plain XMv)
  k_down<64, 0, true><<<dim3(64), blk, 0, stream>>>(nullptr, x, xprev, x_a, A1T, HAB);
  k_up<64, 1><<<gg, blk, 0, stream>>>(HAB, A2T, a0, nullptr, ABF);
  k_down<32, 0, false><<<dim3(64), blk, 0, stream>>>(XMv, nullptr, nullptr, nullptr, V1T, HVB);
  k_up<32, 1><<<gg, blk, 0, stream>>>(HVB, V2T, v0, nullptr, SVB);

  // R projection (XMr in VB region; VB written only later by V-GEMM)
  k_transpose<<<dim3(64, 64), blk, 0, stream>>>(Wr, WT, 2048, 2048);
  k_gemm_big<0><<<gg, blk, 0, stream>>>(XMr, WT,
      nullptr, RB, nullptr, nullptr, nullptr, nullptr, nullptr, nullptr, nullptr);

  // V projection (reads XMv from KB region + SVB; writes VB, killing XMr)
  k_transpose<<<dim3(64, 64), blk, 0, stream>>>(Wv, WT, 2048, 2048);
  k_gemm_big<1><<<gg, blk, 0, stream>>>(XMv, WT,
      nullptr, VB, SVB, vfirst, nullptr, nullptr, nullptr, nullptr, nullptr);

  // K projection (XMk overlays dead SVB; writes KB killing XMv, + AHB/BHB)
  k_prep1<<<dim3(M_), blk, 0, stream>>>(x, xprev, x_k, XMk);
  k_transpose<<<dim3(64, 64), blk, 0, stream>>>(Wk, WT, 2048, 2048);
  k_gemm_big<2><<<gg, blk, 0, stream>>>(XMk, WT,
      nullptr, KB, nullptr, nullptr, ABF, k_k, k_a, AHB, BHB);

  // w-chain (fused mix; WD overlays ABF + XMk, both dead now)
  k_down<64, 1, true><<<dim3(64), blk, 0, stream>>>(nullptr, x, xprev, x_w, W1T, HWB);
  k_up<64, 0><<<gg, blk, 0, stream>>>(HWB, W2T, w0, WD, nullptr);

  // recurrent scan (asm-pinned register pipeline; 2048 one-wave blocks)
  k_scan<<<dim3(2048), dim3(64), 0, stream>>>(RB, WD, KB, VB, AHB, BHB, wkv0, out);

  // g-chain (post-scan; GBF overlays AHB)
  k_down<128, 2, true><<<dim3(64), blk, 0, stream>>>(nullptr, x, xprev, x_g, G1T, HGB);
  k_up<128, 3><<<gg, blk, 0, stream>>>(HGB, G2T, nullptr, nullptr, GBF);

  // GroupNorm + bonus + gate (OUTG overlays BHB)
  k_gn<<<dim3(65536), blk, 0, stream>>>(out, RB, KB, VB, GBF, r_k, lnw, lnb, OUTG);

  // final projection
  k_transpose<<<dim3(64, 64), blk, 0, stream>>>(Wo, WT, 2048, 2048);
  k_gemm_big<3><<<gg, blk, 0, stream>>>(OUTG, WT,
      out, nullptr, nullptr, nullptr, nullptr, nullptr, nullptr, nullptr, nullptr);
}